// Round 16
// baseline (78.267 us; speedup 1.0000x reference)
//
#include <hip/hip_runtime.h>
#include <math.h>

// B=32, C=3, H=W=512. Low-pass keeps freqs {0,1,2,-3,-2,-1} in both dims.
// LAUNCH-LEVEL PIPELINE: 4 groups of 24 (img) channels. One kernel k_mix with
// block-ranges {colsum | proj | tab | out}; successive launches overlap
// group g+1's reads (2.3 TB/s wall) with group g-1's writes (5.3 TB/s):
//   L1: cs(g0)+tab   L2: cs(g1)+proj(g0)   L3: cs(g2)+proj(g1)+out(g0)
//   L4: cs(g3)+proj(g2)+out(g1)   L5: proj(g3)+out(g2)   L6: out(g3)
// Bodies identical to r14 (refcheck'd): colsum = global_load_lds triple-buffer
// vmcnt(2) + raw s_barrier; proj = phasor-recurrence projection; out = T/synth.
//
// ws (floats): tabS @0, Ppart @8192, Apart @65536 (3.15M) ~13 MB.

#define WS_TS 0
#define WS_PP 8192
#define WS_A  65536
constexpr int NPART = 8;

#define CJ1 0.99992470183914450299f
#define CJ2 0.99969881869620422012f
#define CJ3 0.99932238458834954375f
#define CJ4 0.99879545620517239271f
#define SJ1 0.01227153828571992539f
#define SJ2 0.02454122852291228803f
#define SJ3 0.03680722294135883171f
#define SJ4 0.04906767432741801425f

__global__ __launch_bounds__(256) void k_mix(const float* __restrict__ x,
                                             const float* __restrict__ w1,
                                             const float* __restrict__ b1,
                                             const float* __restrict__ w2,
                                             const float* __restrict__ b2,
                                             float* __restrict__ out,
                                             float* __restrict__ ws,
                                             int csImg0, int csN,
                                             int pjImg0, int pjN,
                                             int outB0, int outN, int tab) {
    __shared__ float smem[6144];   // 24 KB, role-dependent layout
    int bid = blockIdx.x;
    int t = threadIdx.x;
    const float TH = 6.28318530717958647692f / 512.0f;

    if (bid < csN) {
        // ---------------- colsum: (img, 64-row hgrp) ----------------
        float* tile = smem;        // 3 buffers x 2048
        float* A = ws + WS_A;
        int img = csImg0 + (bid >> 3);
        int hgrp = bid & 7;
        int wave = t >> 6;
        int lane = t & 63;
        const float* xb = x + (size_t)img * 262144 + (size_t)(hgrp * 64) * 512;

        auto stage = [&](int b, int tt) {
#pragma unroll
            for (int j = 0; j < 2; ++j) {
                int c = wave * 2 + j;
                const float* g = xb + (size_t)tt * 2048 + c * 256 + lane * 4;
                float* l = &tile[b * 2048 + c * 256];
                __builtin_amdgcn_global_load_lds(
                    (const __attribute__((address_space(1))) void*)g,
                    (__attribute__((address_space(3))) void*)l, 16, 0, 0);
            }
        };

        float bc, bs;
        sincosf(TH * (float)(hgrp * 64), &bs, &bc);
        const float CJr[4] = {1.f, CJ1, CJ2, CJ3};
        const float SJr[4] = {0.f, SJ1, SJ2, SJ3};

        float aA[7], aB[7];
#pragma unroll
        for (int c = 0; c < 7; ++c) { aA[c] = 0.f; aB[c] = 0.f; }

        stage(0, 0);
        stage(1, 1);
        asm volatile("s_waitcnt vmcnt(2)" ::: "memory");
        asm volatile("s_barrier" ::: "memory");

        int bcur = 0;
        for (int tt = 0; tt < 16; ++tt) {
            int bnext = bcur + 2; if (bnext >= 3) bnext -= 3;
            if (tt + 2 < 16) stage(bnext, tt + 2);

            const float* tb = &tile[bcur * 2048];
#pragma unroll
            for (int j = 0; j < 4; ++j) {
                float c1 = bc * CJr[j] - bs * SJr[j];
                float s1 = bs * CJr[j] + bc * SJr[j];
                float c2 = c1 * c1 - s1 * s1;
                float s2 = 2.f * c1 * s1;
                float c3 = c1 * c2 - s1 * s2;
                float s3 = s1 * c2 + c1 * s2;
                float xa = tb[j * 512 + t];
                float xc = tb[j * 512 + t + 256];
                aA[0] += xa;
                aA[1] = fmaf(xa, c1, aA[1]);  aA[2] = fmaf(-xa, s1, aA[2]);
                aA[3] = fmaf(xa, c2, aA[3]);  aA[4] = fmaf(-xa, s2, aA[4]);
                aA[5] = fmaf(xa, c3, aA[5]);  aA[6] = fmaf(-xa, s3, aA[6]);
                aB[0] += xc;
                aB[1] = fmaf(xc, c1, aB[1]);  aB[2] = fmaf(-xc, s1, aB[2]);
                aB[3] = fmaf(xc, c2, aB[3]);  aB[4] = fmaf(-xc, s2, aB[4]);
                aB[5] = fmaf(xc, c3, aB[5]);  aB[6] = fmaf(-xc, s3, aB[6]);
            }
            {
                float nb = bc * CJ4 - bs * SJ4;
                bs = bs * CJ4 + bc * SJ4;
                bc = nb;
            }
            if (tt + 2 < 16) asm volatile("s_waitcnt vmcnt(2)" ::: "memory");
            else             asm volatile("s_waitcnt vmcnt(0)" ::: "memory");
            asm volatile("s_barrier" ::: "memory");
            bcur = bcur + 1; if (bcur >= 3) bcur -= 3;
        }

        float* Ab = A + (((size_t)img * NPART + hgrp) * 8) * 512;
        const int pl[7] = {0, 2, 3, 4, 5, 6, 7};
#pragma unroll
        for (int c = 0; c < 7; ++c) {
            Ab[(size_t)pl[c] * 512 + t]       = aA[c];
            Ab[(size_t)pl[c] * 512 + t + 256] = aB[c];
        }
        Ab[(size_t)1 * 512 + t]       = 0.f;
        Ab[(size_t)1 * 512 + t + 256] = 0.f;
        return;
    }

    if (bid < csN + pjN) {
        // ---------------- proj: (img, 64-w seg) ----------------
        float (*As)[64] = (float (*)[64])smem;
        const float* A = ws + WS_A;
        float* Pp = ws + WS_PP;
        int r = bid - csN;
        int img = pjImg0 + (r >> 3);
        int seg = r & 7;
        {
            int plane = t >> 5;
            int wl = (t & 31) * 2;
            float ax = 0.f, ay = 0.f;
#pragma unroll
            for (int hg = 0; hg < NPART; ++hg) {
                float2 v = *(const float2*)(A + (((size_t)img * NPART + hg) * 8 + plane) * 512 + seg * 64 + wl);
                ax += v.x; ay += v.y;
            }
            As[plane][wl] = ax;
            As[plane][wl + 1] = ay;
        }
        __syncthreads();
        if (t < 28) {
            int k = t / 7, mi = t % 7;
            float m = (float)(mi - 3);
            float cm, sm, pc, ps;
            sincosf(-m * TH, &sm, &cm);
            sincosf(-m * TH * (float)(seg * 64), &ps, &pc);
            const float* Ar_ = &As[2 * k][0];
            const float* Ai_ = &As[2 * k + 1][0];
            float pre = 0.f, pim = 0.f;
#pragma unroll 4
            for (int j = 0; j < 64; ++j) {
                float Ar = Ar_[j], Ai = Ai_[j];
                pre += Ar * pc - Ai * ps;
                pim += Ar * ps + Ai * pc;
                float n = pc * cm - ps * sm;
                ps = ps * cm + pc * sm;
                pc = n;
            }
            float* o = Pp + ((size_t)img * 8 + seg) * 56;
            o[t * 2] = pre;
            o[t * 2 + 1] = pim;
        }
        return;
    }

    if (tab && bid == csN + pjN + outN) {
        // ---------------- synthesis twiddle table ----------------
        const int mv[6] = {0, 1, 2, -3, -2, -1};
        for (int h = t; h < 512; h += 256) {
            float* tsp = ws + WS_TS + h * 12;
#pragma unroll
            for (int i = 0; i < 6; ++i) {
                int rr = ((mv[i] * h) % 512 + 512) & 511;
                float s, c;
                sincosf(TH * (float)rr, &s, &c);
                tsp[2 * i] = c; tsp[2 * i + 1] = s;
            }
        }
        return;
    }

    // ---------------- out: (batch b, 4-row tile) ----------------
    {
        const float* tabS = ws + WS_TS;
        const float* Pp = ws + WS_PP;
        float (*F_lds)[56] = (float (*)[56])smem;
        float (*T)[3][12] = (float (*)[3][12])(smem + 168);
        int r = bid - csN - pjN;
        int b = outB0 + (r >> 7);
        int h0 = (r & 127) << 2;

        if (t < 168) {
            int c = t / 56, comp = t % 56;
            const float* pp = Pp + ((size_t)(b * 3 + c) * 8) * 56 + comp;
            float s = 0.f;
#pragma unroll
            for (int g = 0; g < 8; ++g) s += pp[g * 56];
            F_lds[c][comp] = s;
        }

        float rw1[8][3], rb1[8], rw2[3][8], rb2[3];
#pragma unroll
        for (int f_ = 0; f_ < 8; ++f_) {
            rb1[f_] = b1[f_];
#pragma unroll
            for (int c = 0; c < 3; ++c) rw1[f_][c] = w1[f_ * 3 + c];
        }
#pragma unroll
        for (int c = 0; c < 3; ++c) {
            rb2[c] = b2[c];
#pragma unroll
            for (int f_ = 0; f_ < 8; ++f_) rw2[c][f_] = w2[c * 8 + f_];
        }
        __syncthreads();

        if (t < 72) {
            int rl = t / 18, rem = t % 18;
            int c = rem / 6, kc = rem % 6;
            int h = h0 + rl;
            const float* th = tabS + h * 12;
            int m_kc = (kc < 3) ? kc : kc - 6;
            const float inv = 1.0f / (512.0f * 512.0f);
            float tre = 0.f, tim = 0.f;
#pragma unroll
            for (int kr = 0; kr < 6; ++kr) {
                int kk, mi; float csign;
                if (kr < 3) { kk = kr;     mi = m_kc + 3; csign =  1.f; }
                else        { kk = 6 - kr; mi = 3 - m_kc; csign = -1.f; }
                int pair = kk * 7 + mi;
                float fr = F_lds[c][pair * 2] * inv;
                float fi = F_lds[c][pair * 2 + 1] * csign * inv;
                float cc = th[kr * 2], ss = th[kr * 2 + 1];
                tre += fr * cc - fi * ss;
                tim += fr * ss + fi * cc;
            }
            T[rl][c][kc * 2]     = tre;
            T[rl][c][kc * 2 + 1] = tim;
        }
        __syncthreads();

        int rl = t >> 6, lane = t & 63;
        int h = h0 + rl;
        float A0r[3], A0i[3], U1r[3], U1i[3], V1r[3], V1i[3];
        float U2r[3], U2i[3], V2r[3], V2i[3], Br[3], Bi[3];
#pragma unroll
        for (int c = 0; c < 3; ++c) {
            const float* Tc = T[rl][c];
            A0r[c] = Tc[0];  A0i[c] = Tc[1];
            float t1r = Tc[2],  t1i = Tc[3];
            float t2r = Tc[4],  t2i = Tc[5];
            float bmr = Tc[6],  bmi = Tc[7];
            float m2r = Tc[8],  m2i = Tc[9];
            float m1r = Tc[10], m1i = Tc[11];
            U1r[c] = t1r + m1r; U1i[c] = t1i + m1i;
            V1r[c] = t1r - m1r; V1i[c] = t1i - m1i;
            U2r[c] = t2r + m2r; U2i[c] = t2i + m2i;
            V2r[c] = t2r - m2r; V2i[c] = t2i - m2i;
            Br[c] = bmr; Bi[c] = bmi;
        }
        const float* tw = tabS + lane * 12;
        float c1 = tw[2], s1 = tw[3];
        float c2 = tw[4], s2 = tw[5];
        float c3 = tw[6], s3 = -tw[7];
        const float K = 0.70710678118654752440f;
        float* ob = out + ((size_t)(b * 3) * 512 + h) * 512;

#pragma unroll
        for (int j = 0; j < 8; ++j) {
            int w = lane + 64 * j;
            float lp[3];
#pragma unroll
            for (int c = 0; c < 3; ++c) {
                float re = A0r[c] + U1r[c] * c1 - V1i[c] * s1
                                  + U2r[c] * c2 - V2i[c] * s2
                                  + Br[c] * c3 + Bi[c] * s3;
                float im = A0i[c] + U1i[c] * c1 + V1r[c] * s1
                                  + U2i[c] * c2 + V2r[c] * s2
                                  + Bi[c] * c3 - Br[c] * s3;
                lp[c] = sqrtf(re * re + im * im);
            }
            float hid[8];
#pragma unroll
            for (int f_ = 0; f_ < 8; ++f_) {
                float v = rb1[f_] + lp[0] * rw1[f_][0] + lp[1] * rw1[f_][1] + lp[2] * rw1[f_][2];
                hid[f_] = fmaxf(v, 0.0f);
            }
#pragma unroll
            for (int c = 0; c < 3; ++c) {
                float y = rb2[c] + lp[c];
#pragma unroll
                for (int f_ = 0; f_ < 8; ++f_) y += hid[f_] * rw2[c][f_];
                y = fminf(fmaxf(y, 0.0f), 1.0f);
                ob[(size_t)c * 262144 + w] = y;
            }
            if (j < 7) {
                float nc1 = K * (c1 - s1), ns1 = K * (c1 + s1);
                float nc2 = -s2,           ns2 = c2;
                float nc3 = -K * (c3 + s3), ns3 = K * (c3 - s3);
                c1 = nc1; s1 = ns1; c2 = nc2; s2 = ns2; c3 = nc3; s3 = ns3;
            }
        }
    }
}

extern "C" void kernel_launch(void* const* d_in, const int* in_sizes, int n_in,
                              void* d_out, int out_size, void* d_ws, size_t ws_size,
                              hipStream_t stream) {
    const float* x  = (const float*)d_in[0];
    const float* w1 = (const float*)d_in[1];
    const float* b1 = (const float*)d_in[2];
    const float* w2 = (const float*)d_in[3];
    const float* b2 = (const float*)d_in[4];
    float* out = (float*)d_out;
    float* ws = (float*)d_ws;

    // groups of 24 imgs (= 8 batch elems); cs=192 blocks, pj=192, out=1024
    auto L = [&](int csI, int csN, int pjI, int pjN, int ob0, int oN, int tab) {
        int grid = csN + pjN + oN + (tab ? 1 : 0);
        hipLaunchKernelGGL(k_mix, dim3(grid), dim3(256), 0, stream,
                           x, w1, b1, w2, b2, out, ws,
                           csI, csN, pjI, pjN, ob0, oN, tab);
    };
    L( 0, 192,  0,   0,  0,    0, 1);   // cs g0 + tab
    L(24, 192,  0, 192,  0,    0, 0);   // cs g1 + pj g0
    L(48, 192, 24, 192,  0, 1024, 0);   // cs g2 + pj g1 + out g0
    L(72, 192, 48, 192,  8, 1024, 0);   // cs g3 + pj g2 + out g1
    L( 0,   0, 72, 192, 16, 1024, 0);   // pj g3 + out g2
    L( 0,   0,  0,   0, 24, 1024, 0);   // out g3
}

// Round 17
// 63.524 us; speedup vs baseline: 1.2321x; 1.2321x over previous
//
#include <hip/hip_runtime.h>
#include <math.h>

// B=32, C=3, H=W=512. Low-pass keeps freqs {0,1,2,-3,-2,-1} in both dims.
// Pipeline (3 kernels) — r14 structure (best measured: 64.0 us), 7-plane trim:
//   k_colsum: per (img, 64-row hgrp): 16 tiles of 4 rows staged into LDS via
//             __builtin_amdgcn_global_load_lds (width 16), triple buffered,
//             counted s_waitcnt vmcnt(2) + raw s_barrier. Compute from LDS;
//             twiddles from block-uniform base phasor x compile-time
//             rotations -> Apart[img][8][plane 7][512]  (k=0 imag == 0
//             dropped; planes: s0, ar1, ai1, ar2, ai2, ar3, ai3)
//   k_proj:   768 blocks = (img, 64-w seg): reduce 8 partials -> As LDS
//             (row 7 zeroed for k=0 imag); 28 threads project (k,m) pairs by
//             phasor recurrence -> Ppart[img][seg][56]. Block 768 builds tabS.
//   k_out:    sum 8 seg-partials -> F; per-row T[c][kc]; per pixel synth via
//             register phasor recurrence, |.|, MLP 3->8 relu ->3, +lp, clip.
//
// ws (floats): tabS @0, Ppart @8192, Apart @65536 (2.76M) ~11 MB.

#define WS_TS 0
#define WS_PP 8192
#define WS_A  65536
constexpr int NPART = 8;

// cos/sin(2*pi*n/512)
#define CJ1 0.99992470183914450299f
#define CJ2 0.99969881869620422012f
#define CJ3 0.99932238458834954375f
#define CJ4 0.99879545620517239271f
#define SJ1 0.01227153828571992539f
#define SJ2 0.02454122852291228803f
#define SJ3 0.03680722294135883171f
#define SJ4 0.04906767432741801425f

// Block = (img, hgrp of 64 rows). 16 tiles x 4 rows, LDS triple-buffer,
// counted vmcnt + raw barriers.
__global__ __launch_bounds__(256) void k_colsum(const float* __restrict__ x,
                                                float* __restrict__ ws) {
    __shared__ float tile[3 * 2048];     // 3 buffers x 4 rows x 512 = 24 KB
    float* A = ws + WS_A;
    int img = blockIdx.x >> 3;
    int hgrp = blockIdx.x & 7;
    int t = threadIdx.x;
    int wave = t >> 6;
    int lane = t & 63;
    const float* xb = x + (size_t)img * 262144 + (size_t)(hgrp * 64) * 512;

    auto stage = [&](int b, int tt) {
#pragma unroll
        for (int j = 0; j < 2; ++j) {
            int c = wave * 2 + j;
            const float* g = xb + (size_t)tt * 2048 + c * 256 + lane * 4;
            float* l = &tile[b * 2048 + c * 256];
            __builtin_amdgcn_global_load_lds(
                (const __attribute__((address_space(1))) void*)g,
                (__attribute__((address_space(3))) void*)l, 16, 0, 0);
        }
    };

    const float TH = 6.28318530717958647692f / 512.0f;
    float bc, bs;                         // base phasor e^{i theta R0}
    sincosf(TH * (float)(hgrp * 64), &bs, &bc);
    const float CJr[4] = {1.f, CJ1, CJ2, CJ3};
    const float SJr[4] = {0.f, SJ1, SJ2, SJ3};

    float aA[7], aB[7];
#pragma unroll
    for (int c = 0; c < 7; ++c) { aA[c] = 0.f; aB[c] = 0.f; }

    stage(0, 0);
    stage(1, 1);
    asm volatile("s_waitcnt vmcnt(2)" ::: "memory");
    asm volatile("s_barrier" ::: "memory");

    int bcur = 0;
    for (int tt = 0; tt < 16; ++tt) {
        int bnext = bcur + 2; if (bnext >= 3) bnext -= 3;
        if (tt + 2 < 16) stage(bnext, tt + 2);

        const float* tb = &tile[bcur * 2048];
#pragma unroll
        for (int j = 0; j < 4; ++j) {
            float c1 = bc * CJr[j] - bs * SJr[j];
            float s1 = bs * CJr[j] + bc * SJr[j];
            float c2 = c1 * c1 - s1 * s1;
            float s2 = 2.f * c1 * s1;
            float c3 = c1 * c2 - s1 * s2;
            float s3 = s1 * c2 + c1 * s2;
            float xa = tb[j * 512 + t];
            float xc = tb[j * 512 + t + 256];
            aA[0] += xa;
            aA[1] = fmaf(xa, c1, aA[1]);  aA[2] = fmaf(-xa, s1, aA[2]);
            aA[3] = fmaf(xa, c2, aA[3]);  aA[4] = fmaf(-xa, s2, aA[4]);
            aA[5] = fmaf(xa, c3, aA[5]);  aA[6] = fmaf(-xa, s3, aA[6]);
            aB[0] += xc;
            aB[1] = fmaf(xc, c1, aB[1]);  aB[2] = fmaf(-xc, s1, aB[2]);
            aB[3] = fmaf(xc, c2, aB[3]);  aB[4] = fmaf(-xc, s2, aB[4]);
            aB[5] = fmaf(xc, c3, aB[5]);  aB[6] = fmaf(-xc, s3, aB[6]);
        }
        {   // advance base phasor by 4 rows
            float nb = bc * CJ4 - bs * SJ4;
            bs = bs * CJ4 + bc * SJ4;
            bc = nb;
        }

        if (tt + 2 < 16) asm volatile("s_waitcnt vmcnt(2)" ::: "memory");
        else             asm volatile("s_waitcnt vmcnt(0)" ::: "memory");
        asm volatile("s_barrier" ::: "memory");
        bcur = bcur + 1; if (bcur >= 3) bcur -= 3;
    }

    // planes: 0=s0, 1=ar1, 2=ai1, 3=ar2, 4=ai2, 5=ar3, 6=ai3
    float* Ab = A + ((size_t)(img * NPART + hgrp) * 7) * 512;
#pragma unroll
    for (int c = 0; c < 7; ++c) {
        Ab[(size_t)c * 512 + t]       = aA[c];
        Ab[(size_t)c * 512 + t + 256] = aB[c];
    }
}

// Blocks 0..767 = (img, seg): reduce 8 partials for 64 w, project 28 pairs.
// Block 768: build tabS.
__global__ __launch_bounds__(256) void k_proj(float* __restrict__ ws) {
    int t = threadIdx.x;
    const float TH = 6.28318530717958647692f / 512.0f;
    if (blockIdx.x == 768) {
        const int mv[6] = {0, 1, 2, -3, -2, -1};
        for (int h = t; h < 512; h += 256) {
            float* tsp = ws + WS_TS + h * 12;
#pragma unroll
            for (int i = 0; i < 6; ++i) {
                int r = ((mv[i] * h) % 512 + 512) & 511;
                float s, c;
                sincosf(TH * (float)r, &s, &c);
                tsp[2 * i] = c; tsp[2 * i + 1] = s;
            }
        }
        return;
    }
    __shared__ float As[8][64];          // rows 0..6 = planes; row 7 = zeros
    const float* A = ws + WS_A;
    float* Pp = ws + WS_PP;
    int img = blockIdx.x >> 3;
    int seg = blockIdx.x & 7;

    {
        int plane = t >> 5;              // 0..7
        int wl = (t & 31) * 2;
        if (plane < 7) {
            float ax = 0.f, ay = 0.f;
#pragma unroll
            for (int hg = 0; hg < NPART; ++hg) {
                float2 v = *(const float2*)(A + ((size_t)(img * NPART + hg) * 7 + plane) * 512 + seg * 64 + wl);
                ax += v.x; ay += v.y;
            }
            As[plane][wl] = ax;
            As[plane][wl + 1] = ay;
        } else {
            As[7][wl] = 0.f;
            As[7][wl + 1] = 0.f;
        }
    }
    __syncthreads();

    if (t < 28) {
        int k = t / 7, mi = t % 7;
        const int ridx[4] = {0, 1, 3, 5};
        const int iidx[4] = {7, 2, 4, 6};   // k=0 imag = zero row
        float m = (float)(mi - 3);
        float cm, sm, pc, ps;
        sincosf(-m * TH, &sm, &cm);
        sincosf(-m * TH * (float)(seg * 64), &ps, &pc);
        const float* Ar_ = &As[ridx[k]][0];
        const float* Ai_ = &As[iidx[k]][0];
        float pre = 0.f, pim = 0.f;
#pragma unroll 4
        for (int j = 0; j < 64; ++j) {
            float Ar = Ar_[j], Ai = Ai_[j];
            pre += Ar * pc - Ai * ps;
            pim += Ar * ps + Ai * pc;
            float n = pc * cm - ps * sm;
            ps = ps * cm + pc * sm;
            pc = n;
        }
        float* o = Pp + ((size_t)img * 8 + seg) * 56;
        o[t * 2] = pre;
        o[t * 2 + 1] = pim;
    }
}

__global__ __launch_bounds__(256) void k_out(const float* __restrict__ ws,
                                             const float* __restrict__ w1,
                                             const float* __restrict__ b1,
                                             const float* __restrict__ w2,
                                             const float* __restrict__ b2,
                                             float* __restrict__ out) {
    const float* tabS = ws + WS_TS;
    const float* Pp = ws + WS_PP;
    __shared__ float F_lds[3][56];
    __shared__ float T[4][3][12];
    int t = threadIdx.x;
    int blk = blockIdx.x;
    int b = blk >> 7;
    int h0 = (blk & 127) << 2;

    if (t < 168) {
        int c = t / 56, comp = t % 56;
        const float* pp = Pp + ((size_t)(b * 3 + c) * 8) * 56 + comp;
        float s = 0.f;
#pragma unroll
        for (int g = 0; g < 8; ++g) s += pp[g * 56];
        F_lds[c][comp] = s;
    }

    float rw1[8][3], rb1[8], rw2[3][8], rb2[3];
#pragma unroll
    for (int f_ = 0; f_ < 8; ++f_) {
        rb1[f_] = b1[f_];
#pragma unroll
        for (int c = 0; c < 3; ++c) rw1[f_][c] = w1[f_ * 3 + c];
    }
#pragma unroll
    for (int c = 0; c < 3; ++c) {
        rb2[c] = b2[c];
#pragma unroll
        for (int f_ = 0; f_ < 8; ++f_) rw2[c][f_] = w2[c * 8 + f_];
    }
    __syncthreads();

    if (t < 72) {
        int rl = t / 18, rem = t % 18;
        int c = rem / 6, kc = rem % 6;
        int h = h0 + rl;
        const float* th = tabS + h * 12;
        int m_kc = (kc < 3) ? kc : kc - 6;
        const float inv = 1.0f / (512.0f * 512.0f);
        float tre = 0.f, tim = 0.f;
#pragma unroll
        for (int kr = 0; kr < 6; ++kr) {
            int kk, mi; float csign;
            if (kr < 3) { kk = kr;     mi = m_kc + 3; csign =  1.f; }
            else        { kk = 6 - kr; mi = 3 - m_kc; csign = -1.f; }
            int pair = kk * 7 + mi;
            float fr = F_lds[c][pair * 2] * inv;
            float fi = F_lds[c][pair * 2 + 1] * csign * inv;
            float cc = th[kr * 2], ss = th[kr * 2 + 1];
            tre += fr * cc - fi * ss;
            tim += fr * ss + fi * cc;
        }
        T[rl][c][kc * 2]     = tre;
        T[rl][c][kc * 2 + 1] = tim;
    }
    __syncthreads();

    int rl = t >> 6, lane = t & 63;
    int h = h0 + rl;
    float A0r[3], A0i[3], U1r[3], U1i[3], V1r[3], V1i[3];
    float U2r[3], U2i[3], V2r[3], V2i[3], Br[3], Bi[3];
#pragma unroll
    for (int c = 0; c < 3; ++c) {
        const float* Tc = T[rl][c];
        A0r[c] = Tc[0];  A0i[c] = Tc[1];
        float t1r = Tc[2],  t1i = Tc[3];
        float t2r = Tc[4],  t2i = Tc[5];
        float bmr = Tc[6],  bmi = Tc[7];
        float m2r = Tc[8],  m2i = Tc[9];
        float m1r = Tc[10], m1i = Tc[11];
        U1r[c] = t1r + m1r; U1i[c] = t1i + m1i;
        V1r[c] = t1r - m1r; V1i[c] = t1i - m1i;
        U2r[c] = t2r + m2r; U2i[c] = t2i + m2i;
        V2r[c] = t2r - m2r; V2i[c] = t2i - m2i;
        Br[c] = bmr; Bi[c] = bmi;
    }
    const float* tw = tabS + lane * 12;
    float c1 = tw[2], s1 = tw[3];
    float c2 = tw[4], s2 = tw[5];
    float c3 = tw[6], s3 = -tw[7];
    const float K = 0.70710678118654752440f;
    float* ob = out + ((size_t)(b * 3) * 512 + h) * 512;

#pragma unroll
    for (int j = 0; j < 8; ++j) {
        int w = lane + 64 * j;
        float lp[3];
#pragma unroll
        for (int c = 0; c < 3; ++c) {
            float re = A0r[c] + U1r[c] * c1 - V1i[c] * s1
                              + U2r[c] * c2 - V2i[c] * s2
                              + Br[c] * c3 + Bi[c] * s3;
            float im = A0i[c] + U1i[c] * c1 + V1r[c] * s1
                              + U2i[c] * c2 + V2r[c] * s2
                              + Bi[c] * c3 - Br[c] * s3;
            lp[c] = sqrtf(re * re + im * im);
        }
        float hid[8];
#pragma unroll
        for (int f_ = 0; f_ < 8; ++f_) {
            float v = rb1[f_] + lp[0] * rw1[f_][0] + lp[1] * rw1[f_][1] + lp[2] * rw1[f_][2];
            hid[f_] = fmaxf(v, 0.0f);
        }
#pragma unroll
        for (int c = 0; c < 3; ++c) {
            float y = rb2[c] + lp[c];
#pragma unroll
            for (int f_ = 0; f_ < 8; ++f_) y += hid[f_] * rw2[c][f_];
            y = fminf(fmaxf(y, 0.0f), 1.0f);
            ob[(size_t)c * 262144 + w] = y;
        }
        if (j < 7) {
            float nc1 = K * (c1 - s1), ns1 = K * (c1 + s1);
            float nc2 = -s2,           ns2 = c2;
            float nc3 = -K * (c3 + s3), ns3 = K * (c3 - s3);
            c1 = nc1; s1 = ns1; c2 = nc2; s2 = ns2; c3 = nc3; s3 = ns3;
        }
    }
}

extern "C" void kernel_launch(void* const* d_in, const int* in_sizes, int n_in,
                              void* d_out, int out_size, void* d_ws, size_t ws_size,
                              hipStream_t stream) {
    const float* x  = (const float*)d_in[0];
    const float* w1 = (const float*)d_in[1];
    const float* b1 = (const float*)d_in[2];
    const float* w2 = (const float*)d_in[3];
    const float* b2 = (const float*)d_in[4];
    float* out = (float*)d_out;
    float* ws = (float*)d_ws;

    hipLaunchKernelGGL(k_colsum, dim3(96 * NPART), dim3(256), 0, stream, x, ws);
    hipLaunchKernelGGL(k_proj, dim3(769), dim3(256), 0, stream, ws);
    hipLaunchKernelGGL(k_out, dim3(4096), dim3(256), 0, stream, ws, w1, b1, w2, b2, out);
}